// Round 3
// baseline (3331.235 us; speedup 1.0000x reference)
//
#include <hip/hip_runtime.h>
#include <math.h>

// Problem constants (fixed by reference: B=32,T=1024,D=256,K=1024)
#define N_ROWS 32768
#define DIM    256
#define KCODES 1024

#define BM 128   // rows per block
#define BK 256   // codes per k-tile
#define BD 32    // d-chunk staged in LDS per tile
#define AST 36   // padded row stride (144 B, 16B-aligned; rows hit distinct bank quads)
#define BST 36
#define NTILES 32  // 4 kt * 8 dc

// ---------------------------------------------------------------------------
// Exact replica of numpy pairwise sum-of-squares (n=256) — proven correct R2.
__global__ __launch_bounds__(256) void rowsum_sq_kernel(const float* __restrict__ src,
                                                        float* __restrict__ dst,
                                                        int nrows) {
    __shared__ float sq[4][260];
    const int wave = threadIdx.x >> 6;
    const int lane = threadIdx.x & 63;
    const int row  = blockIdx.x * 4 + wave;
    if (row >= nrows) return;

    const float4* rp = (const float4*)(src + (size_t)row * DIM);
    float4 v = rp[lane];
    sq[wave][lane * 4 + 0] = v.x * v.x;
    sq[wave][lane * 4 + 1] = v.y * v.y;
    sq[wave][lane * 4 + 2] = v.z * v.z;
    sq[wave][lane * 4 + 3] = v.w * v.w;
    if (lane < 8) {
#pragma clang fp contract(off)
        const int j = lane;
        float rA = sq[wave][j];
#pragma unroll
        for (int m = 1; m < 16; ++m) rA += sq[wave][8 * m + j];
        float rB = sq[wave][128 + j];
#pragma unroll
        for (int m = 1; m < 16; ++m) rB += sq[wave][128 + 8 * m + j];
        rA = rA + __shfl_xor(rA, 1, 64);
        rA = rA + __shfl_xor(rA, 2, 64);
        rA = rA + __shfl_xor(rA, 4, 64);
        rB = rB + __shfl_xor(rB, 1, 64);
        rB = rB + __shfl_xor(rB, 2, 64);
        rB = rB + __shfl_xor(rB, 4, 64);
        if (j == 0) dst[row] = rA + rB;
    }
}

// ---------------------------------------------------------------------------
// Fused scores + argmin + gather.
// 512 threads = 8 waves. Lane micro-layout: px = l&7 (code grp), py = l>>3
// (row grp). ry = (w&1)*8+py in [0,16), cx = (w>>1)*8+px in [0,32).
// Thread tile: rows {ry+16i}, codes {cx+32j}, i,j in [0,8).
// LDS reads: per wave, 8 distinct consecutive-row addresses (distinct bank
// quads, stride 36) x 8-way broadcast -> conflict-free, minimal traffic.
// Pipeline: 32 flat tiles (kt,dc), double-buffered LDS, register prefetch,
// ONE barrier per tile; global-load latency hidden behind compute.
__global__ __launch_bounds__(512, 2) void vq_kernel(const float* __restrict__ X,
                                                    const float* __restrict__ E,
                                                    const float* __restrict__ e2g,
                                                    const float* __restrict__ x2g,
                                                    float* __restrict__ out0,
                                                    float* __restrict__ out1,
                                                    float* __restrict__ out2) {
    __shared__ float a_tile[2][BM][AST];   // 36864 B
    __shared__ float b_tile[2][BK][BST];   // 73728 B
    __shared__ float val_s[BM][5];         // 2560 B (pad 5: conflict-free)
    __shared__ int   idx_s[BM][5];         // 2560 B
    __shared__ int   idx_lds[BM];          // 512 B   -> total 116224 B

    const int tid  = threadIdx.x;
    const int w    = tid >> 6;
    const int l    = tid & 63;
    const int px   = l & 7;
    const int py   = l >> 3;
    const int ry   = (w & 1) * 8 + py;    // row group   [0,16)
    const int cx   = (w >> 1) * 8 + px;   // code group  [0,32)
    const int row0 = blockIdx.x * BM;

    float4 pa[2], pb[4];
    auto load_regs = [&](int t) {
        const int kt = t >> 3, dc = t & 7;
#pragma unroll
        for (int s = 0; s < 2; ++s) {
            int q = tid + s * 512, r = q >> 3, g = q & 7;
            pa[s] = *(const float4*)(X + (size_t)(row0 + r) * DIM + dc * BD + g * 4);
        }
#pragma unroll
        for (int s = 0; s < 4; ++s) {
            int q = tid + s * 512, r = q >> 3, g = q & 7;
            pb[s] = *(const float4*)(E + (size_t)((kt << 8) + r) * DIM + dc * BD + g * 4);
        }
    };
    auto store_lds = [&](int buf) {
#pragma unroll
        for (int s = 0; s < 2; ++s) {
            int q = tid + s * 512, r = q >> 3, g = q & 7;
            *(float4*)(&a_tile[buf][r][g * 4]) = pa[s];
        }
#pragma unroll
        for (int s = 0; s < 4; ++s) {
            int q = tid + s * 512, r = q >> 3, g = q & 7;
            *(float4*)(&b_tile[buf][r][g * 4]) = pb[s];
        }
    };

    float x2r[8];
#pragma unroll
    for (int i = 0; i < 8; ++i) x2r[i] = x2g[row0 + ry + 16 * i];

    float runval[8];
    int   runidx[8];
#pragma unroll
    for (int i = 0; i < 8; ++i) { runval[i] = INFINITY; runidx[i] = 0; }

    float acc[8][8];
#pragma unroll
    for (int i = 0; i < 8; ++i)
#pragma unroll
        for (int j = 0; j < 8; ++j) acc[i][j] = 0.f;

    // prologue: tile0 -> buf0; tile1 loads in flight
    load_regs(0);
    store_lds(0);
    load_regs(1);
    __syncthreads();

    for (int t = 0; t < NTILES; ++t) {
        const int cur = t & 1;
        // compute on buf[cur]
#pragma unroll
        for (int dd = 0; dd < BD; dd += 4) {
            float4 af[8], bf[8];
#pragma unroll
            for (int i = 0; i < 8; ++i)
                af[i] = *(const float4*)(&a_tile[cur][ry + 16 * i][dd]);
#pragma unroll
            for (int j = 0; j < 8; ++j)
                bf[j] = *(const float4*)(&b_tile[cur][cx + 32 * j][dd]);
#pragma unroll
            for (int i = 0; i < 8; ++i)
#pragma unroll
                for (int j = 0; j < 8; ++j) {
                    acc[i][j] = fmaf(af[i].x, bf[j].x, acc[i][j]);
                    acc[i][j] = fmaf(af[i].y, bf[j].y, acc[i][j]);
                    acc[i][j] = fmaf(af[i].z, bf[j].z, acc[i][j]);
                    acc[i][j] = fmaf(af[i].w, bf[j].w, acc[i][j]);
                }
        }
        // write prefetched tile t+1 into the other buffer; issue loads t+2
        if (t < NTILES - 1) {
            store_lds(cur ^ 1);
            if (t < NTILES - 2) load_regs(t + 2);
        }
        // kt boundary: fold scores into running argmin, reset acc.
        // Score = fp32(e2 - 2*dot) + x2, matching numpy rounding (proven R2).
        if ((t & 7) == 7) {
            const int kt = t >> 3;
#pragma unroll
            for (int j = 0; j < 8; ++j) {
                const int kg = (kt << 8) + cx + 32 * j;
                const float e2v = e2g[kg];
#pragma unroll
                for (int i = 0; i < 8; ++i) {
                    float t1 = e2v - 2.0f * acc[i][j];
                    float s  = t1 + x2r[i];
                    if (s < runval[i]) { runval[i] = s; runidx[i] = kg; }
                    acc[i][j] = 0.f;
                }
            }
        }
        __syncthreads();
    }

    // reduce: within-wave across px (8 lanes, lex-min -> lowest index on tie),
    // then cross-wave across the 4 code quads via LDS.
#pragma unroll
    for (int i = 0; i < 8; ++i) {
        float v  = runval[i];
        int   ix = runidx[i];
#pragma unroll
        for (int off = 1; off <= 4; off <<= 1) {
            float ov = __shfl_xor(v, off, 64);
            int   oi = __shfl_xor(ix, off, 64);
            if (ov < v || (ov == v && oi < ix)) { v = ov; ix = oi; }
        }
        if (px == 0) {
            val_s[ry + 16 * i][w >> 1] = v;
            idx_s[ry + 16 * i][w >> 1] = ix;
        }
    }
    __syncthreads();
    if (tid < BM) {
        float bv = val_s[tid][0];
        int   bi = idx_s[tid][0];
#pragma unroll
        for (int q = 1; q < 4; ++q) {
            float qv = val_s[tid][q];
            int   qi = idx_s[tid][q];
            if (qv < bv || (qv == bv && qi < bi)) { bv = qv; bi = qi; }
        }
        idx_lds[tid] = bi;
        out2[row0 + tid] = (float)bi;
    }
    __syncthreads();

    // epilogue: gather embedding rows to both outputs
#pragma unroll
    for (int it = 0; it < (BM * (DIM / 4)) / 512; ++it) {   // 16 iters
        int f = tid + it * 512;
        int r = f >> 6;
        int p = f & 63;
        int ix = idx_lds[r];
        float4 v = *(const float4*)(E + (size_t)ix * DIM + p * 4);
        size_t o = (size_t)(row0 + r) * DIM + (size_t)p * 4;
        *(float4*)(out0 + o) = v;
        *(float4*)(out1 + o) = v;
    }
}

// ---------------------------------------------------------------------------
extern "C" void kernel_launch(void* const* d_in, const int* in_sizes, int n_in,
                              void* d_out, int out_size, void* d_ws, size_t ws_size,
                              hipStream_t stream) {
    const float* X = (const float*)d_in[0];
    const float* E = (const float*)d_in[1];
    float* e2   = (float*)d_ws;                    // KCODES floats
    float* x2   = e2 + KCODES;                     // N_ROWS floats
    float* out0 = (float*)d_out;                   // embed_idx   [N, D]
    float* out1 = out0 + (size_t)N_ROWS * DIM;     // embed_idx_qx[N, D]
    float* out2 = out1 + (size_t)N_ROWS * DIM;     // quantized_idx as float [N]

    rowsum_sq_kernel<<<dim3(KCODES / 4), dim3(256), 0, stream>>>(E, e2, KCODES);
    rowsum_sq_kernel<<<dim3(N_ROWS / 4), dim3(256), 0, stream>>>(X, x2, N_ROWS);
    vq_kernel<<<dim3(N_ROWS / BM), dim3(512), 0, stream>>>(X, E, e2, x2,
                                                           out0, out1, out2);
}

// Round 4
// 365.156 us; speedup vs baseline: 9.1228x; 9.1228x over previous
//
#include <hip/hip_runtime.h>
#include <math.h>

// Problem constants (fixed by reference: B=32,T=1024,D=256,K=1024)
#define N_ROWS 32768
#define DIM    256
#define KCODES 1024

#define BM 64    // rows per block (grid 512 -> 2 blocks/CU)
#define BK 256   // codes per k-tile (loop 4x for full K)
#define BD 32    // d-chunk staged in LDS
#define AST 36   // padded row stride: consecutive rows (delta<8) never alias banks
#define BST 36

// ---------------------------------------------------------------------------
// Exact replica of numpy pairwise sum-of-squares (n=256) — proven correct R2.
__global__ __launch_bounds__(256) void rowsum_sq_kernel(const float* __restrict__ src,
                                                        float* __restrict__ dst,
                                                        int nrows) {
    __shared__ float sq[4][260];
    const int wave = threadIdx.x >> 6;
    const int lane = threadIdx.x & 63;
    const int row  = blockIdx.x * 4 + wave;
    if (row >= nrows) return;

    const float4* rp = (const float4*)(src + (size_t)row * DIM);
    float4 v = rp[lane];
    sq[wave][lane * 4 + 0] = v.x * v.x;
    sq[wave][lane * 4 + 1] = v.y * v.y;
    sq[wave][lane * 4 + 2] = v.z * v.z;
    sq[wave][lane * 4 + 3] = v.w * v.w;
    if (lane < 8) {
#pragma clang fp contract(off)
        const int j = lane;
        float rA = sq[wave][j];
#pragma unroll
        for (int m = 1; m < 16; ++m) rA += sq[wave][8 * m + j];
        float rB = sq[wave][128 + j];
#pragma unroll
        for (int m = 1; m < 16; ++m) rB += sq[wave][128 + 8 * m + j];
        rA = rA + __shfl_xor(rA, 1, 64);
        rA = rA + __shfl_xor(rA, 2, 64);
        rA = rA + __shfl_xor(rA, 4, 64);
        rB = rB + __shfl_xor(rB, 1, 64);
        rB = rB + __shfl_xor(rB, 2, 64);
        rB = rB + __shfl_xor(rB, 4, 64);
        if (j == 0) dst[row] = rA + rB;
    }
}

// ---------------------------------------------------------------------------
// Fused scores + argmin + gather. R2's proven 2-barrier single-buffer
// structure; NO cross-loop register prefetch (R3 spilled: 10.5 GB scratch).
// 256 threads = 4 waves. Lane layout: px = l&7 (code grp), py = l>>3 (row
// grp), cx = w*8+px in [0,32). Thread tile: rows {py+8i}, codes {cx+32j}.
// LDS reads: 8 consecutive-row addresses (stride 36, no bank alias) x 8-way
// broadcast -> conflict-free and ~8x less unique-address LDS traffic.
__global__ __launch_bounds__(256) void vq_kernel(const float* __restrict__ X,
                                                 const float* __restrict__ E,
                                                 const float* __restrict__ e2g,
                                                 const float* __restrict__ x2g,
                                                 float* __restrict__ out0,
                                                 float* __restrict__ out1,
                                                 float* __restrict__ out2) {
    __shared__ float a_tile[BM][AST];   //  9216 B
    __shared__ float b_tile[BK][BST];   // 36864 B
    __shared__ float val_s[BM][5];      //  1280 B (pad 5: conflict-free)
    __shared__ int   idx_s[BM][5];      //  1280 B
    __shared__ int   idx_lds[BM];       //   256 B  -> ~49 KB total, 2+ blocks/CU

    const int tid  = threadIdx.x;
    const int w    = tid >> 6;    // wave 0..3
    const int l    = tid & 63;
    const int px   = l & 7;       // code sub-group
    const int py   = l >> 3;      // row group 0..7
    const int cx   = w * 8 + px;  // code group 0..31
    const int row0 = blockIdx.x * BM;

    float x2r[8];
#pragma unroll
    for (int i = 0; i < 8; ++i) x2r[i] = x2g[row0 + py + 8 * i];

    float runval[8];
    int   runidx[8];
#pragma unroll
    for (int i = 0; i < 8; ++i) { runval[i] = INFINITY; runidx[i] = 0; }

    for (int kt = 0; kt < KCODES / BK; ++kt) {
        float acc[8][8];
#pragma unroll
        for (int i = 0; i < 8; ++i)
#pragma unroll
            for (int j = 0; j < 8; ++j) acc[i][j] = 0.f;

        float e2r[8];
#pragma unroll
        for (int j = 0; j < 8; ++j) e2r[j] = e2g[kt * BK + cx + 32 * j];

        for (int dc = 0; dc < DIM / BD; ++dc) {
            __syncthreads();
            // stage A: 64 rows x 32 d = 512 float4, 2 per thread
#pragma unroll
            for (int s = 0; s < 2; ++s) {
                int q = tid + s * 256;
                int r = q >> 3, g = q & 7;
                float4 v = *(const float4*)(X + (size_t)(row0 + r) * DIM + dc * BD + g * 4);
                *(float4*)(&a_tile[r][g * 4]) = v;
            }
            // stage B: 256 codes x 32 d = 2048 float4, 8 per thread
#pragma unroll
            for (int s = 0; s < 8; ++s) {
                int q = tid + s * 256;
                int r = q >> 3, g = q & 7;
                float4 v = *(const float4*)(E + (size_t)(kt * BK + r) * DIM + dc * BD + g * 4);
                *(float4*)(&b_tile[r][g * 4]) = v;
            }
            __syncthreads();
#pragma unroll
            for (int dd = 0; dd < BD; dd += 4) {
                float4 af[8], bf[8];
#pragma unroll
                for (int i = 0; i < 8; ++i)
                    af[i] = *(const float4*)(&a_tile[py + 8 * i][dd]);
#pragma unroll
                for (int j = 0; j < 8; ++j)
                    bf[j] = *(const float4*)(&b_tile[cx + 32 * j][dd]);
#pragma unroll
                for (int i = 0; i < 8; ++i)
#pragma unroll
                    for (int j = 0; j < 8; ++j) {
                        acc[i][j] = fmaf(af[i].x, bf[j].x, acc[i][j]);
                        acc[i][j] = fmaf(af[i].y, bf[j].y, acc[i][j]);
                        acc[i][j] = fmaf(af[i].z, bf[j].z, acc[i][j]);
                        acc[i][j] = fmaf(af[i].w, bf[j].w, acc[i][j]);
                    }
            }
        }
        // fold into running argmin. Score = fp32(e2 - 2*dot) + x2 (numpy
        // rounding, proven R2). k ascending + strict < = first-occurrence.
#pragma unroll
        for (int j = 0; j < 8; ++j) {
            const int kg = kt * BK + cx + 32 * j;
#pragma unroll
            for (int i = 0; i < 8; ++i) {
                float t1 = e2r[j] - 2.0f * acc[i][j];
                float s  = t1 + x2r[i];
                if (s < runval[i]) { runval[i] = s; runidx[i] = kg; }
            }
        }
    }

    // reduce: within-wave across px (lanes l = py*8 + px; xor 1,2,4 stays in
    // the py group; lex-min -> lowest index), then cross-wave via LDS.
#pragma unroll
    for (int i = 0; i < 8; ++i) {
        float v  = runval[i];
        int   ix = runidx[i];
#pragma unroll
        for (int off = 1; off <= 4; off <<= 1) {
            float ov = __shfl_xor(v, off, 64);
            int   oi = __shfl_xor(ix, off, 64);
            if (ov < v || (ov == v && oi < ix)) { v = ov; ix = oi; }
        }
        if (px == 0) {
            val_s[py + 8 * i][w] = v;
            idx_s[py + 8 * i][w] = ix;
        }
    }
    __syncthreads();
    if (tid < BM) {
        float bv = val_s[tid][0];
        int   bi = idx_s[tid][0];
#pragma unroll
        for (int q = 1; q < 4; ++q) {
            float qv = val_s[tid][q];
            int   qi = idx_s[tid][q];
            if (qv < bv || (qv == bv && qi < bi)) { bv = qv; bi = qi; }
        }
        idx_lds[tid] = bi;
        out2[row0 + tid] = (float)bi;
    }
    __syncthreads();

    // epilogue: gather embedding rows to both outputs (64 rows x 64 float4)
#pragma unroll
    for (int it = 0; it < (BM * (DIM / 4)) / 256; ++it) {   // 16 iters
        int f = tid + it * 256;
        int r = f >> 6;
        int p = f & 63;
        int ix = idx_lds[r];
        float4 v = *(const float4*)(E + (size_t)ix * DIM + p * 4);
        size_t o = (size_t)(row0 + r) * DIM + (size_t)p * 4;
        *(float4*)(out0 + o) = v;
        *(float4*)(out1 + o) = v;
    }
}

// ---------------------------------------------------------------------------
extern "C" void kernel_launch(void* const* d_in, const int* in_sizes, int n_in,
                              void* d_out, int out_size, void* d_ws, size_t ws_size,
                              hipStream_t stream) {
    const float* X = (const float*)d_in[0];
    const float* E = (const float*)d_in[1];
    float* e2   = (float*)d_ws;                    // KCODES floats
    float* x2   = e2 + KCODES;                     // N_ROWS floats
    float* out0 = (float*)d_out;                   // embed_idx   [N, D]
    float* out1 = out0 + (size_t)N_ROWS * DIM;     // embed_idx_qx[N, D]
    float* out2 = out1 + (size_t)N_ROWS * DIM;     // quantized_idx as float [N]

    rowsum_sq_kernel<<<dim3(KCODES / 4), dim3(256), 0, stream>>>(E, e2, KCODES);
    rowsum_sq_kernel<<<dim3(N_ROWS / 4), dim3(256), 0, stream>>>(X, x2, N_ROWS);
    vq_kernel<<<dim3(N_ROWS / BM), dim3(256), 0, stream>>>(X, E, e2, x2,
                                                           out0, out1, out2);
}

// Round 5
// 324.944 us; speedup vs baseline: 10.2517x; 1.1238x over previous
//
#include <hip/hip_runtime.h>
#include <math.h>

// Problem constants (fixed by reference: B=32,T=1024,D=256,K=1024)
#define N_ROWS 32768
#define DIM    256
#define KCODES 1024

#define BM 64    // rows per block
#define BK 256   // codes per k-tile (loop 4x for full K)
#define BD 32    // d-chunk staged in LDS
#define AST 36   // padded row stride: consecutive rows (delta<8) never alias banks
#define BST 36

// ---------------------------------------------------------------------------
// Exact replica of numpy pairwise sum-of-squares (n=256) — proven correct R2.
__global__ __launch_bounds__(256) void rowsum_sq_kernel(const float* __restrict__ src,
                                                        float* __restrict__ dst,
                                                        int nrows) {
    __shared__ float sq[4][260];
    const int wave = threadIdx.x >> 6;
    const int lane = threadIdx.x & 63;
    const int row  = blockIdx.x * 4 + wave;
    if (row >= nrows) return;

    const float4* rp = (const float4*)(src + (size_t)row * DIM);
    float4 v = rp[lane];
    sq[wave][lane * 4 + 0] = v.x * v.x;
    sq[wave][lane * 4 + 1] = v.y * v.y;
    sq[wave][lane * 4 + 2] = v.z * v.z;
    sq[wave][lane * 4 + 3] = v.w * v.w;
    if (lane < 8) {
#pragma clang fp contract(off)
        const int j = lane;
        float rA = sq[wave][j];
#pragma unroll
        for (int m = 1; m < 16; ++m) rA += sq[wave][8 * m + j];
        float rB = sq[wave][128 + j];
#pragma unroll
        for (int m = 1; m < 16; ++m) rB += sq[wave][128 + 8 * m + j];
        rA = rA + __shfl_xor(rA, 1, 64);
        rA = rA + __shfl_xor(rA, 2, 64);
        rA = rA + __shfl_xor(rA, 4, 64);
        rB = rB + __shfl_xor(rB, 1, 64);
        rB = rB + __shfl_xor(rB, 2, 64);
        rB = rB + __shfl_xor(rB, 4, 64);
        if (j == 0) dst[row] = rA + rB;
    }
}

// ---------------------------------------------------------------------------
// Fused scores + argmin + gather. R4 structure + fragment PING-PONG over dd:
// while FMAs consume fragment set X (dims s), set Y (dims s+1) is loading —
// overlapping the LDS-return pipe with the VALU pipe, which R4 serialized
// (both pipes ~50% -> 51% VALUBusy at 315us). FMA order per accumulator is
// unchanged (dims ascending) -> bitwise-identical scores.
// __launch_bounds__(256,2): VGPR cap 256 (need ~220; R3 spilled at a 128 cap).
__global__ __launch_bounds__(256, 2) void vq_kernel(const float* __restrict__ X,
                                                    const float* __restrict__ E,
                                                    const float* __restrict__ e2g,
                                                    const float* __restrict__ x2g,
                                                    float* __restrict__ out0,
                                                    float* __restrict__ out1,
                                                    float* __restrict__ out2) {
    __shared__ float a_tile[BM][AST];   //  9216 B
    __shared__ float b_tile[BK][BST];   // 36864 B
    __shared__ float val_s[BM][5];      //  1280 B
    __shared__ int   idx_s[BM][5];      //  1280 B
    __shared__ int   idx_lds[BM];       //   256 B

    const int tid  = threadIdx.x;
    const int w    = tid >> 6;    // wave 0..3
    const int l    = tid & 63;
    const int px   = l & 7;       // code sub-group
    const int py   = l >> 3;      // row group 0..7
    const int cx   = w * 8 + px;  // code group 0..31
    const int row0 = blockIdx.x * BM;

    float x2r[8];
#pragma unroll
    for (int i = 0; i < 8; ++i) x2r[i] = x2g[row0 + py + 8 * i];

    float runval[8];
    int   runidx[8];
#pragma unroll
    for (int i = 0; i < 8; ++i) { runval[i] = INFINITY; runidx[i] = 0; }

    for (int kt = 0; kt < KCODES / BK; ++kt) {
        float acc[8][8];
#pragma unroll
        for (int i = 0; i < 8; ++i)
#pragma unroll
            for (int j = 0; j < 8; ++j) acc[i][j] = 0.f;

        for (int dc = 0; dc < DIM / BD; ++dc) {
            __syncthreads();
            // stage A: 64 rows x 32 d = 512 float4, 2 per thread
#pragma unroll
            for (int s = 0; s < 2; ++s) {
                int q = tid + s * 256;
                int r = q >> 3, g = q & 7;
                float4 v = *(const float4*)(X + (size_t)(row0 + r) * DIM + dc * BD + g * 4);
                *(float4*)(&a_tile[r][g * 4]) = v;
            }
            // stage B: 256 codes x 32 d = 2048 float4, 8 per thread
#pragma unroll
            for (int s = 0; s < 8; ++s) {
                int q = tid + s * 256;
                int r = q >> 3, g = q & 7;
                float4 v = *(const float4*)(E + (size_t)(kt * BK + r) * DIM + dc * BD + g * 4);
                *(float4*)(&b_tile[r][g * 4]) = v;
            }
            __syncthreads();

            float4 afA[8], bfA[8], afB[8], bfB[8];
            auto lf = [&](float4 (&af)[8], float4 (&bf)[8], int dd) {
#pragma unroll
                for (int i = 0; i < 8; ++i)
                    af[i] = *(const float4*)(&a_tile[py + 8 * i][dd]);
#pragma unroll
                for (int j = 0; j < 8; ++j)
                    bf[j] = *(const float4*)(&b_tile[cx + 32 * j][dd]);
            };
            auto comp = [&](float4 (&af)[8], float4 (&bf)[8]) {
#pragma unroll
                for (int i = 0; i < 8; ++i)
#pragma unroll
                    for (int j = 0; j < 8; ++j) {
                        acc[i][j] = fmaf(af[i].x, bf[j].x, acc[i][j]);
                        acc[i][j] = fmaf(af[i].y, bf[j].y, acc[i][j]);
                        acc[i][j] = fmaf(af[i].z, bf[j].z, acc[i][j]);
                        acc[i][j] = fmaf(af[i].w, bf[j].w, acc[i][j]);
                    }
            };

            lf(afA, bfA, 0);
#pragma unroll
            for (int s = 0; s < 8; s += 2) {
                if (s + 1 < 8) lf(afB, bfB, (s + 1) * 4);
                comp(afA, bfA);                      // dims 4s..4s+3
                if (s + 2 < 8) lf(afA, bfA, (s + 2) * 4);
                comp(afB, bfB);                      // dims 4s+4..4s+7
            }
        }
        // fold into running argmin. Score = fp32(e2 - 2*dot) + x2 (numpy
        // rounding, proven R2). k ascending + strict < = first-occurrence.
#pragma unroll
        for (int j = 0; j < 8; ++j) {
            const int kg = kt * BK + cx + 32 * j;
            const float e2v = e2g[kg];
#pragma unroll
            for (int i = 0; i < 8; ++i) {
                float t1 = e2v - 2.0f * acc[i][j];
                float s  = t1 + x2r[i];
                if (s < runval[i]) { runval[i] = s; runidx[i] = kg; }
            }
        }
    }

    // reduce: within-wave across px (xor 1,2,4 stays in the py group;
    // lex-min -> lowest index), then cross-wave via LDS.
#pragma unroll
    for (int i = 0; i < 8; ++i) {
        float v  = runval[i];
        int   ix = runidx[i];
#pragma unroll
        for (int off = 1; off <= 4; off <<= 1) {
            float ov = __shfl_xor(v, off, 64);
            int   oi = __shfl_xor(ix, off, 64);
            if (ov < v || (ov == v && oi < ix)) { v = ov; ix = oi; }
        }
        if (px == 0) {
            val_s[py + 8 * i][w] = v;
            idx_s[py + 8 * i][w] = ix;
        }
    }
    __syncthreads();
    if (tid < BM) {
        float bv = val_s[tid][0];
        int   bi = idx_s[tid][0];
#pragma unroll
        for (int q = 1; q < 4; ++q) {
            float qv = val_s[tid][q];
            int   qi = idx_s[tid][q];
            if (qv < bv || (qv == bv && qi < bi)) { bv = qv; bi = qi; }
        }
        idx_lds[tid] = bi;
        out2[row0 + tid] = (float)bi;
    }
    __syncthreads();

    // epilogue: gather embedding rows to both outputs (64 rows x 64 float4)
#pragma unroll
    for (int it = 0; it < (BM * (DIM / 4)) / 256; ++it) {   // 16 iters
        int f = tid + it * 256;
        int r = f >> 6;
        int p = f & 63;
        int ix = idx_lds[r];
        float4 v = *(const float4*)(E + (size_t)ix * DIM + p * 4);
        size_t o = (size_t)(row0 + r) * DIM + (size_t)p * 4;
        *(float4*)(out0 + o) = v;
        *(float4*)(out1 + o) = v;
    }
}

// ---------------------------------------------------------------------------
extern "C" void kernel_launch(void* const* d_in, const int* in_sizes, int n_in,
                              void* d_out, int out_size, void* d_ws, size_t ws_size,
                              hipStream_t stream) {
    const float* X = (const float*)d_in[0];
    const float* E = (const float*)d_in[1];
    float* e2   = (float*)d_ws;                    // KCODES floats
    float* x2   = e2 + KCODES;                     // N_ROWS floats
    float* out0 = (float*)d_out;                   // embed_idx   [N, D]
    float* out1 = out0 + (size_t)N_ROWS * DIM;     // embed_idx_qx[N, D]
    float* out2 = out1 + (size_t)N_ROWS * DIM;     // quantized_idx as float [N]

    rowsum_sq_kernel<<<dim3(KCODES / 4), dim3(256), 0, stream>>>(E, e2, KCODES);
    rowsum_sq_kernel<<<dim3(N_ROWS / 4), dim3(256), 0, stream>>>(X, x2, N_ROWS);
    vq_kernel<<<dim3(N_ROWS / BM), dim3(256), 0, stream>>>(X, E, e2, x2,
                                                           out0, out1, out2);
}